// Round 3
// baseline (609.089 us; speedup 1.0000x reference)
//
#include <hip/hip_runtime.h>
#include <cstdint>
#include <cstddef>

typedef __attribute__((ext_vector_type(8))) short bf16x8;
typedef __attribute__((ext_vector_type(8))) unsigned short us8;
typedef __attribute__((ext_vector_type(4))) float f32x4;

#define TSEQ 2048

__device__ __forceinline__ unsigned short f2bf(float f) {
  union { float f; uint32_t u; } v; v.f = f;
  uint32_t u = v.u;
  uint32_t r = (u + 0x7FFFu + ((u >> 16) & 1u)) >> 16;
  return (unsigned short)r;
}
__device__ __forceinline__ unsigned short f2bf_trunc(float f) {
  union { float f; uint32_t u; } v; v.f = f;
  return (unsigned short)(v.u >> 16);
}
__device__ __forceinline__ float bf2f(unsigned short h) {
  union { uint32_t u; float f; } v; v.u = ((uint32_t)h) << 16;
  return v.f;
}

__device__ __forceinline__ void async16(const void* g, void* l) {
  __builtin_amdgcn_global_load_lds(
      (const __attribute__((address_space(1))) unsigned int*)g,
      (__attribute__((address_space(3))) unsigned int*)l,
      16, 0, 0);
}

#define FENCE asm volatile("" ::: "memory")

// ---------------------------------------------------------------------------
// x (fp32) -> xb (bf16), 16 elems/thread
// ---------------------------------------------------------------------------
__global__ __launch_bounds__(256) void cvt_x(
    const float* __restrict__ in, unsigned short* __restrict__ out)
{
  const size_t i = ((size_t)blockIdx.x * 256 + threadIdx.x) * 16;
  f32x4 a0 = *(const f32x4*)(in + i);
  f32x4 a1 = *(const f32x4*)(in + i + 4);
  f32x4 a2 = *(const f32x4*)(in + i + 8);
  f32x4 a3 = *(const f32x4*)(in + i + 12);
  us8 lo, hi;
#pragma unroll
  for (int j = 0; j < 4; j++) {
    lo[j] = f2bf(a0[j]); lo[j + 4] = f2bf(a1[j]);
    hi[j] = f2bf(a2[j]); hi[j + 4] = f2bf(a3[j]);
  }
  *(us8*)(out + i) = lo;
  *(us8*)(out + i + 8) = hi;
}

// ---------------------------------------------------------------------------
// out(C x R bf16) = transpose of in(R x C fp32)
// ---------------------------------------------------------------------------
__global__ __launch_bounds__(256) void transpose_w(
    const float* __restrict__ in, unsigned short* __restrict__ out,
    int R, int C)
{
  __shared__ unsigned short tile[32][33];
  const int bx = blockIdx.x * 32;
  const int by = blockIdx.y * 32;
  const int tx = threadIdx.x & 31;
  const int ty = threadIdx.x >> 5;
#pragma unroll
  for (int r = ty; r < 32; r += 8)
    tile[r][tx] = f2bf(in[(size_t)(by + r) * C + bx + tx]);
  __syncthreads();
#pragma unroll
  for (int r = ty; r < 32; r += 8)
    out[(size_t)(bx + r) * R + by + tx] = tile[tx][r];
}

// ---------------------------------------------------------------------------
// Legacy 128x128 gemm (proj GEMM: 512 blocks).
// ---------------------------------------------------------------------------
template <int CF32>
__global__ __launch_bounds__(256) void gemm_bt(
    const unsigned short* __restrict__ A,
    const unsigned short* __restrict__ Bt,
    void* __restrict__ Cv,
    int M, int N, int K, int ldc)
{
  __shared__ unsigned short As[2][128 * 32];
  __shared__ unsigned short Bs[2][128 * 32];
  const int tid  = threadIdx.x;
  const int lane = tid & 63;
  const int w    = tid >> 6;
  const int m0   = blockIdx.y * 128;
  const int n0   = blockIdx.x * 128;
  const int wm   = (w & 1) * 64;
  const int wn   = (w >> 1) * 64;

  const int srow = lane >> 2;
  const int scol = (lane & 3) * 8;
  const unsigned short* ga0 = A  + (size_t)(m0 + w * 16 + srow) * K + scol;
  const unsigned short* ga1 = ga0 + (size_t)64 * K;
  const unsigned short* gb0 = Bt + (size_t)(n0 + w * 16 + srow) * K + scol;
  const unsigned short* gb1 = gb0 + (size_t)64 * K;

  f32x4 acc[4][4];
#pragma unroll
  for (int i = 0; i < 4; i++)
#pragma unroll
    for (int j = 0; j < 4; j++) acc[i][j] = (f32x4){0.f, 0.f, 0.f, 0.f};

  const int frow = lane & 15;
  const int fcol = (lane >> 4) * 8;

  for (int kt = 0; kt < K; kt += 64) {
    __syncthreads();
    async16(ga0 + kt,      &As[0][w * 512]);
    async16(ga1 + kt,      &As[0][(4 + w) * 512]);
    async16(ga0 + kt + 32, &As[1][w * 512]);
    async16(ga1 + kt + 32, &As[1][(4 + w) * 512]);
    async16(gb0 + kt,      &Bs[0][w * 512]);
    async16(gb1 + kt,      &Bs[0][(4 + w) * 512]);
    async16(gb0 + kt + 32, &Bs[1][w * 512]);
    async16(gb1 + kt + 32, &Bs[1][(4 + w) * 512]);
    __syncthreads();

#pragma unroll
    for (int h = 0; h < 2; h++) {
      bf16x8 af[4], bfr[4];
#pragma unroll
      for (int i = 0; i < 4; i++)
        af[i] = *(const bf16x8*)&As[h][(wm + i * 16 + frow) * 32 + fcol];
#pragma unroll
      for (int i = 0; i < 4; i++)
        bfr[i] = *(const bf16x8*)&Bs[h][(wn + i * 16 + frow) * 32 + fcol];
#pragma unroll
      for (int mi = 0; mi < 4; mi++)
#pragma unroll
        for (int ni = 0; ni < 4; ni++)
          acc[mi][ni] = __builtin_amdgcn_mfma_f32_16x16x32_bf16(
              af[mi], bfr[ni], acc[mi][ni], 0, 0, 0);
    }
  }

  const int crow0 = m0 + wm + (lane >> 4) * 4;
  const int ccol0 = n0 + wn + (lane & 15);
  if (CF32) {
    float* Cf = (float*)Cv;
#pragma unroll
    for (int mi = 0; mi < 4; mi++)
#pragma unroll
      for (int i = 0; i < 4; i++) {
        const int row = crow0 + mi * 16 + i;
#pragma unroll
        for (int ni = 0; ni < 4; ni++)
          Cf[(size_t)row * ldc + ccol0 + ni * 16] = acc[mi][ni][i];
      }
  } else {
    unsigned short* Cb = (unsigned short*)Cv;
#pragma unroll
    for (int mi = 0; mi < 4; mi++)
#pragma unroll
      for (int i = 0; i < 4; i++) {
        const int row = crow0 + mi * 16 + i;
#pragma unroll
        for (int ni = 0; ni < 4; ni++)
          Cb[(size_t)row * ldc + ccol0 + ni * 16] = f2bf(acc[mi][ni][i]);
      }
  }
}

// ---------------------------------------------------------------------------
// 256x256 BK=64 phase-pipelined GEMM, v3.
// Round-3 change: ds_reads issued ONE PHASE AHEAD with COUNTED lgkmcnt so the
// LDS drain overlaps the previous MFMA cluster (r2 counters showed full
// serialization: 2483 MFMA + 2304 ds cyc/K-tile = measured 5175).
//   Read groups: G0 = a03+b01 (12, issued prev P3) ; G1 = b23 (4, @P0) ;
//                G2 = a47 (8, @P1).
//   Quadrants:  P0 a03xb01 | P1 a03xb23 | P2 a47xb01 | P3 a47xb23
//   (P3 operands disjoint from G0' targets -> next-tile reads overlap MFMA3.)
//   Stage hazards (cross-wave gate in parens): A0,A2@P1 (B0); B0,B1@P2 (B0);
//   B2,B3@P3 (B1); A1,A3@P3 (B2). vmcnt(8) once per K-tile before B3.
//   sched_barrier(0) after each waitcnt pins issue order (rule #18).
// ---------------------------------------------------------------------------
__device__ __forceinline__ void stage8(
    const unsigned short* gA, const unsigned short* gB,
    unsigned short* asb, unsigned short* bsb, int K, int kt, int lw)
{
#pragma unroll
  for (int j = 0; j < 4; j++)
    async16(gA + (size_t)j * 64 * K + (size_t)kt * 64, asb + j * 4096 + lw);
#pragma unroll
  for (int j = 0; j < 4; j++)
    async16(gB + (size_t)j * 64 * K + (size_t)kt * 64, bsb + j * 4096 + lw);
}

__global__ __launch_bounds__(512, 2) void gemm256(
    const unsigned short* __restrict__ A,
    const unsigned short* __restrict__ Bt,
    unsigned short* __restrict__ C,
    int K, int ldc, int ntiles, int nwg)
{
  __shared__ unsigned short As[2][256 * 64];
  __shared__ unsigned short Bs[2][256 * 64];

  // XCD-aware bijective swizzle (nwg % 8 == 0 by construction)
  int wg = blockIdx.x;
  wg = (wg & 7) * (nwg >> 3) + (wg >> 3);
  const int m0 = (wg / ntiles) * 256;
  const int n0 = (wg % ntiles) * 256;

  const int tid  = threadIdx.x;
  const int lane = tid & 63;
  const int w    = tid >> 6;
  const int wr   = w & 1;   // 2 M-groups
  const int wc   = w >> 1;  // 4 N-groups

  // staging map: thread t -> row t>>3, 16B-slot (t ^ (t>>3)) & 7
  const int srow  = tid >> 3;
  const int sslot = (tid ^ srow) & 7;
  const unsigned short* gA = A  + (size_t)(m0 + srow) * K + sslot * 8;
  const unsigned short* gB = Bt + (size_t)(n0 + srow) * K + sslot * 8;
  const int lw = w * 512;  // wave's 1 KiB slice within an 8 KiB chunk

  f32x4 acc[8][4];
#pragma unroll
  for (int i = 0; i < 8; i++)
#pragma unroll
    for (int j = 0; j < 4; j++) acc[i][j] = (f32x4){0.f, 0.f, 0.f, 0.f};

  const int frow = lane & 15;
  const int fq16 = (lane >> 4) * 16;         // byte offset of 16B k-slot
  const int axr  = (frow & 7) << 4;          // XOR key
  const int arow = (wr * 128 + frow) * 128;  // byte base, mi=0 kh=0
  const int brow = (wc * 64 + frow) * 128;

#define RDA(buf, mi, kh) \
  (*(const bf16x8*)((const char*)&As[buf][0] + ((arow + (mi) * 2048 + (kh) * 64 + fq16) ^ axr)))
#define RDB(buf, ni, kh) \
  (*(const bf16x8*)((const char*)&Bs[buf][0] + ((brow + (ni) * 2048 + (kh) * 64 + fq16) ^ axr)))
#define STG_A(c, kt2) async16(gA + (size_t)(c) * 64 * K + (size_t)(kt2) * 64, &As[p][(c) * 4096 + lw])
#define STG_B(c, kt2) async16(gB + (size_t)(c) * 64 * K + (size_t)(kt2) * 64, &Bs[p][(c) * 4096 + lw])

  stage8(gA, gB, &As[0][0], &Bs[0][0], K, 0, lw);
  stage8(gA, gB, &As[1][0], &Bs[1][0], K, 1, lw);
  asm volatile("s_waitcnt vmcnt(8)" ::: "memory");
  __builtin_amdgcn_s_barrier();
  FENCE;

  const int NT = K >> 6;
  bf16x8 a0[4][2], a4[4][2], b0[2][2], b2[2][2];

  // prologue G0 (buf 0): a03 + b01
#pragma unroll
  for (int mi = 0; mi < 4; mi++) { a0[mi][0] = RDA(0, mi, 0); a0[mi][1] = RDA(0, mi, 1); }
#pragma unroll
  for (int ni = 0; ni < 2; ni++) { b0[ni][0] = RDB(0, ni, 0); b0[ni][1] = RDB(0, ni, 1); }

  for (int kt = 0; kt < NT; ++kt) {
    const int p = kt & 1;

    // ---- P0: issue G1 (b23); lgkm(4) [G0 done]; MFMA a03 x b01
#pragma unroll
    for (int ni = 0; ni < 2; ni++) { b2[ni][0] = RDB(p, ni + 2, 0); b2[ni][1] = RDB(p, ni + 2, 1); }
    asm volatile("s_waitcnt lgkmcnt(4)" ::: "memory");
    __builtin_amdgcn_sched_barrier(0);
    __builtin_amdgcn_s_setprio(1);
#pragma unroll
    for (int mi = 0; mi < 4; mi++)
#pragma unroll
      for (int ni = 0; ni < 2; ni++)
#pragma unroll
        for (int kh = 0; kh < 2; kh++)
          acc[mi][ni] = __builtin_amdgcn_mfma_f32_16x16x32_bf16(
              a0[mi][kh], b0[ni][kh], acc[mi][ni], 0, 0, 0);
    __builtin_amdgcn_s_setprio(0);
    __builtin_amdgcn_s_barrier();   // B0
    FENCE;

    // ---- P1: stage A0,A2@kt+2; issue G2 (a47); lgkm(8) [G1 done]; MFMA a03 x b23
    if (kt + 2 < NT) { STG_A(0, kt + 2); STG_A(2, kt + 2); }
#pragma unroll
    for (int mi = 0; mi < 4; mi++) { a4[mi][0] = RDA(p, mi + 4, 0); a4[mi][1] = RDA(p, mi + 4, 1); }
    asm volatile("s_waitcnt lgkmcnt(8)" ::: "memory");
    __builtin_amdgcn_sched_barrier(0);
    __builtin_amdgcn_s_setprio(1);
#pragma unroll
    for (int mi = 0; mi < 4; mi++)
#pragma unroll
      for (int ni = 0; ni < 2; ni++)
#pragma unroll
        for (int kh = 0; kh < 2; kh++)
          acc[mi][ni + 2] = __builtin_amdgcn_mfma_f32_16x16x32_bf16(
              a0[mi][kh], b2[ni][kh], acc[mi][ni + 2], 0, 0, 0);
    __builtin_amdgcn_s_setprio(0);
    __builtin_amdgcn_s_barrier();   // B1
    FENCE;

    // ---- P2: stage B0,B1@kt+2; lgkm(0) [G2 done]; MFMA a47 x b01
    if (kt + 2 < NT) { STG_B(0, kt + 2); STG_B(1, kt + 2); }
    asm volatile("s_waitcnt lgkmcnt(0)" ::: "memory");
    __builtin_amdgcn_sched_barrier(0);
    __builtin_amdgcn_s_setprio(1);
#pragma unroll
    for (int mi = 0; mi < 4; mi++)
#pragma unroll
      for (int ni = 0; ni < 2; ni++)
#pragma unroll
        for (int kh = 0; kh < 2; kh++)
          acc[mi + 4][ni] = __builtin_amdgcn_mfma_f32_16x16x32_bf16(
              a4[mi][kh], b0[ni][kh], acc[mi + 4][ni], 0, 0, 0);
    __builtin_amdgcn_s_setprio(0);
    __builtin_amdgcn_s_barrier();   // B2
    FENCE;

    // ---- P3: stage B2,B3,A1,A3@kt+2; vmcnt(8); B3; issue G0' (next buf);
    //          MFMA a47 x b23 overlaps G0' drain.
    if (kt + 2 < NT) {
      STG_B(2, kt + 2); STG_B(3, kt + 2); STG_A(1, kt + 2); STG_A(3, kt + 2);
      asm volatile("s_waitcnt vmcnt(8)" ::: "memory");   // kt+1 landed; kt+2 in flight
    } else {
      asm volatile("s_waitcnt vmcnt(0)" ::: "memory");   // epilogue drain
    }
    __builtin_amdgcn_s_barrier();   // B3
    FENCE;
    if (kt + 1 < NT) {
      const int pn = p ^ 1;
#pragma unroll
      for (int mi = 0; mi < 4; mi++) { a0[mi][0] = RDA(pn, mi, 0); a0[mi][1] = RDA(pn, mi, 1); }
#pragma unroll
      for (int ni = 0; ni < 2; ni++) { b0[ni][0] = RDB(pn, ni, 0); b0[ni][1] = RDB(pn, ni, 1); }
    }
    __builtin_amdgcn_sched_barrier(0);
    __builtin_amdgcn_s_setprio(1);
#pragma unroll
    for (int mi = 0; mi < 4; mi++)
#pragma unroll
      for (int ni = 0; ni < 2; ni++)
#pragma unroll
        for (int kh = 0; kh < 2; kh++)
          acc[mi + 4][ni + 2] = __builtin_amdgcn_mfma_f32_16x16x32_bf16(
              a4[mi][kh], b2[ni][kh], acc[mi + 4][ni + 2], 0, 0, 0);
    __builtin_amdgcn_s_setprio(0);
  }
#undef RDA
#undef RDB
#undef STG_A
#undef STG_B

  // C/D layout (m89-verified): col = lane&15, row = (lane>>4)*4 + reg
  const int crow0 = m0 + wr * 128 + (lane >> 4) * 4;
  const int ccol0 = n0 + wc * 64 + frow;
#pragma unroll
  for (int mi = 0; mi < 8; mi++)
#pragma unroll
    for (int i = 0; i < 4; i++) {
      const size_t row = (size_t)(crow0 + mi * 16 + i);
#pragma unroll
      for (int ni = 0; ni < 4; ni++)
        C[row * ldc + ccol0 + ni * 16] = f2bf(acc[mi][ni][i]);
    }
}

// ---------------------------------------------------------------------------
// RoPE in-place on qkv cols [0,4096); 1/sqrt(128) folded into q half.
// ---------------------------------------------------------------------------
__global__ __launch_bounds__(256) void rope_qk(unsigned short* __restrict__ qkv)
{
  const int p   = blockIdx.x * 256 + threadIdx.x;
  const int row = p >> 11;
  const int col = (p & 2047) * 2;
  const int t   = row & (TSEQ - 1);
  const int hd  = col & 127;
  const float theta = exp2f((float)hd * -0.1038102531f);
  const float ang   = (float)t * theta;
  float s, c;
  sincosf(ang, &s, &c);
  const float sc = (col < 2048) ? 0.08838834764831845f : 1.0f;
  uint32_t* ptr = (uint32_t*)(qkv + (size_t)row * 6144 + col);
  const uint32_t u = *ptr;
  const float x0 = bf2f((unsigned short)(u & 0xffffu));
  const float x1 = bf2f((unsigned short)(u >> 16));
  const float o0 = (x0 * c - x1 * s) * sc;
  const float o1 = (x1 * c + x0 * s) * sc;
  *ptr = (uint32_t)f2bf(o0) | ((uint32_t)f2bf(o1) << 16);
}

// ---------------------------------------------------------------------------
// Repack V: qkv cols [4096,6144) -> Vtg[b][h][d=128][t=2048]
// ---------------------------------------------------------------------------
__global__ __launch_bounds__(256) void repack_v(
    const unsigned short* __restrict__ qkv, unsigned short* __restrict__ Vtg)
{
  __shared__ unsigned short tile[32][33];
  const int tt = blockIdx.x * 32;
  const int dd = blockIdx.y * 32;
  const int bh = blockIdx.z;
  const int b  = bh >> 4, h = bh & 15;
  const int tx = threadIdx.x & 31;
  const int ty = threadIdx.x >> 5;
#pragma unroll
  for (int r = ty; r < 32; r += 8)
    tile[r][tx] = qkv[(size_t)(b * TSEQ + tt + r) * 6144 + 4096 + h * 128 + dd + tx];
  __syncthreads();
#pragma unroll
  for (int r = ty; r < 32; r += 8)
    Vtg[(size_t)bh * 262144 + (size_t)(dd + r) * TSEQ + tt + tx] = tile[tx][r];
}

// ---------------------------------------------------------------------------
// Flash attention. block = (b,h,128 q-rows), 4 waves x 32 q-rows, K-chunk 64.
// ---------------------------------------------------------------------------
__global__ __launch_bounds__(256) void attn(
    const unsigned short* __restrict__ qkv,  // (4096,6144) rope'd, q pre-scaled
    const unsigned short* __restrict__ Vtg,  // (32,128,2048)
    unsigned short* __restrict__ y)          // (4096,2048)
{
  __shared__ unsigned short Ks[64 * 136];
  __shared__ unsigned short Vs[144 * 72];
  __shared__ unsigned short Ps[4][32 * 72];

  const int tid  = threadIdx.x;
  const int lane = tid & 63;
  const int w    = tid >> 6;
  const int q0   = blockIdx.x * 128;
  const int h    = blockIdx.y;
  const int b    = blockIdx.z;
  const int bh   = b * 16 + h;
  const int quad = lane >> 4;
  const int l15  = lane & 15;
  const int kq   = quad * 8;

  for (int idx = tid; idx < 16 * 72; idx += 256)
    Vs[128 * 72 + idx] = (idx < 72) ? (unsigned short)0x3F80 : (unsigned short)0;

  bf16x8 qa[2][4];
#pragma unroll
  for (int mt = 0; mt < 2; mt++) {
    const unsigned short* gQ =
        qkv + (size_t)(b * TSEQ + q0 + w * 32 + mt * 16 + l15) * 6144 + h * 128 + kq;
#pragma unroll
    for (int dc = 0; dc < 4; dc++) qa[mt][dc] = *(const bf16x8*)(gQ + dc * 32);
  }

  f32x4 ot[2][9];
#pragma unroll
  for (int mt = 0; mt < 2; mt++)
#pragma unroll
    for (int nt = 0; nt < 9; nt++) ot[mt][nt] = (f32x4){0.f, 0.f, 0.f, 0.f};

  const int krow = tid >> 2;
  const int kd   = (tid & 3) * 32;
  const unsigned short* gK = qkv + (size_t)(b * TSEQ) * 6144 + 2048 + h * 128 + kd;
  const int vd = tid >> 1;
  const int vc = (tid & 1) * 32;
  const unsigned short* gVt = Vtg + (size_t)bh * 262144 + (size_t)vd * TSEQ + vc;

  for (int kb = 0; kb < TSEQ; kb += 64) {
    __syncthreads();
    {
      const unsigned short* pk = gK + (size_t)(kb + krow) * 6144;
#pragma unroll
      for (int j = 0; j < 4; j++)
        *(us8*)&Ks[krow * 136 + kd + j * 8] = *(const us8*)(pk + j * 8);
      const unsigned short* pv = gVt + kb;
#pragma unroll
      for (int j = 0; j < 4; j++)
        *(us8*)&Vs[vd * 72 + vc + j * 8] = *(const us8*)(pv + j * 8);
    }
    __syncthreads();

    f32x4 s[2][4];
#pragma unroll
    for (int mt = 0; mt < 2; mt++)
#pragma unroll
      for (int ct = 0; ct < 4; ct++) s[mt][ct] = (f32x4){0.f, 0.f, 0.f, 0.f};
#pragma unroll
    for (int dc = 0; dc < 4; dc++) {
#pragma unroll
      for (int ct = 0; ct < 4; ct++) {
        bf16x8 kf = *(const bf16x8*)&Ks[(ct * 16 + l15) * 136 + dc * 32 + kq];
        s[0][ct] = __builtin_amdgcn_mfma_f32_16x16x32_bf16(qa[0][dc], kf, s[0][ct], 0, 0, 0);
        s[1][ct] = __builtin_amdgcn_mfma_f32_16x16x32_bf16(qa[1][dc], kf, s[1][ct], 0, 0, 0);
      }
    }

    unsigned short* pw = &Ps[w][0];
#pragma unroll
    for (int mt = 0; mt < 2; mt++)
#pragma unroll
      for (int ct = 0; ct < 4; ct++)
#pragma unroll
        for (int i = 0; i < 4; i++)
          pw[(mt * 16 + quad * 4 + i) * 72 + ct * 16 + l15] =
              f2bf_trunc(__expf(fminf(s[mt][ct][i], 30.f)));

    __asm__ volatile("s_waitcnt lgkmcnt(0)" ::: "memory");

#pragma unroll
    for (int kc = 0; kc < 2; kc++) {
      bf16x8 pa0 = *(const bf16x8*)&pw[(l15) * 72 + kc * 32 + kq];
      bf16x8 pa1 = *(const bf16x8*)&pw[(16 + l15) * 72 + kc * 32 + kq];
#pragma unroll
      for (int nt = 0; nt < 9; nt++) {
        bf16x8 vb = *(const bf16x8*)&Vs[(nt * 16 + l15) * 72 + kc * 32 + kq];
        ot[0][nt] = __builtin_amdgcn_mfma_f32_16x16x32_bf16(pa0, vb, ot[0][nt], 0, 0, 0);
        ot[1][nt] = __builtin_amdgcn_mfma_f32_16x16x32_bf16(pa1, vb, ot[1][nt], 0, 0, 0);
      }
    }
  }

#pragma unroll
  for (int mt = 0; mt < 2; mt++) {
    unsigned short* gy =
        y + (size_t)(b * TSEQ + q0 + w * 32 + mt * 16 + quad * 4) * 2048 + h * 128 + l15;
#pragma unroll
    for (int i = 0; i < 4; i++) {
      const float inv = 1.0f / __shfl(ot[mt][8][i], lane & 48);
#pragma unroll
      for (int nt = 0; nt < 8; nt++)
        gy[(size_t)i * 2048 + nt * 16] = f2bf(ot[mt][nt][i] * inv);
    }
  }
}

// ---------------------------------------------------------------------------
extern "C" void kernel_launch(void* const* d_in, const int* in_sizes, int n_in,
                              void* d_out, int out_size, void* d_ws, size_t ws_size,
                              hipStream_t stream)
{
  const float* x      = (const float*)d_in[0];
  const float* w_attn = (const float*)d_in[1];
  const float* w_proj = (const float*)d_in[2];

  if (ws_size < 67108864u) return;

  char* ws = (char*)d_ws;
  unsigned short* qkv = (unsigned short*)(ws);              // 48 MiB
  unsigned short* xb  = (unsigned short*)(ws + 50331648);   // 16 MiB (then y)
  unsigned short* y   = xb;
  unsigned short* wT2 = (unsigned short*)(ws);              // 8 MiB, after attn
  unsigned short* wTa = (unsigned short*)d_out;             // 24 MiB scratch
  unsigned short* Vtg = (unsigned short*)d_out;             // 16 MiB scratch

  transpose_w<<<dim3(192, 64), 256, 0, stream>>>(w_attn, wTa, 2048, 6144);
  cvt_x<<<dim3(2048), 256, 0, stream>>>(x, xb);
  // QKV: M=4096 N=6144 K=2048, 16 x 24 = 384 tiles of 256^2
  gemm256<<<dim3(384), 512, 0, stream>>>(xb, wTa, qkv, 2048, 6144, 24, 384);
  rope_qk<<<dim3(32768), 256, 0, stream>>>(qkv);
  repack_v<<<dim3(64, 4, 32), 256, 0, stream>>>(qkv, Vtg);
  attn<<<dim3(16, 16, 2), 256, 0, stream>>>(qkv, Vtg, y);
  transpose_w<<<dim3(64, 64), 256, 0, stream>>>(w_proj, wT2, 2048, 2048);
  gemm_bt<1><<<dim3(16, 32), 256, 0, stream>>>(y, wT2, d_out, 4096, 2048, 2048, 2048);
}

// Round 4
// 606.258 us; speedup vs baseline: 1.0047x; 1.0047x over previous
//
#include <hip/hip_runtime.h>
#include <cstdint>
#include <cstddef>

typedef __attribute__((ext_vector_type(8))) short bf16x8;
typedef __attribute__((ext_vector_type(8))) unsigned short us8;
typedef __attribute__((ext_vector_type(4))) float f32x4;

#define TSEQ 2048

__device__ __forceinline__ unsigned short f2bf(float f) {
  union { float f; uint32_t u; } v; v.f = f;
  uint32_t u = v.u;
  uint32_t r = (u + 0x7FFFu + ((u >> 16) & 1u)) >> 16;
  return (unsigned short)r;
}
__device__ __forceinline__ unsigned short f2bf_trunc(float f) {
  union { float f; uint32_t u; } v; v.f = f;
  return (unsigned short)(v.u >> 16);
}
__device__ __forceinline__ float bf2f(unsigned short h) {
  union { uint32_t u; float f; } v; v.u = ((uint32_t)h) << 16;
  return v.f;
}

__device__ __forceinline__ void async16(const void* g, void* l) {
  __builtin_amdgcn_global_load_lds(
      (const __attribute__((address_space(1))) unsigned int*)g,
      (__attribute__((address_space(3))) unsigned int*)l,
      16, 0, 0);
}

#define FENCE asm volatile("" ::: "memory")

// ---------------------------------------------------------------------------
// x (fp32) -> xb (bf16), 16 elems/thread
// ---------------------------------------------------------------------------
__global__ __launch_bounds__(256) void cvt_x(
    const float* __restrict__ in, unsigned short* __restrict__ out)
{
  const size_t i = ((size_t)blockIdx.x * 256 + threadIdx.x) * 16;
  f32x4 a0 = *(const f32x4*)(in + i);
  f32x4 a1 = *(const f32x4*)(in + i + 4);
  f32x4 a2 = *(const f32x4*)(in + i + 8);
  f32x4 a3 = *(const f32x4*)(in + i + 12);
  us8 lo, hi;
#pragma unroll
  for (int j = 0; j < 4; j++) {
    lo[j] = f2bf(a0[j]); lo[j + 4] = f2bf(a1[j]);
    hi[j] = f2bf(a2[j]); hi[j + 4] = f2bf(a3[j]);
  }
  *(us8*)(out + i) = lo;
  *(us8*)(out + i + 8) = hi;
}

// ---------------------------------------------------------------------------
// out(C x R bf16) = transpose of in(R x C fp32)
// ---------------------------------------------------------------------------
__global__ __launch_bounds__(256) void transpose_w(
    const float* __restrict__ in, unsigned short* __restrict__ out,
    int R, int C)
{
  __shared__ unsigned short tile[32][33];
  const int bx = blockIdx.x * 32;
  const int by = blockIdx.y * 32;
  const int tx = threadIdx.x & 31;
  const int ty = threadIdx.x >> 5;
#pragma unroll
  for (int r = ty; r < 32; r += 8)
    tile[r][tx] = f2bf(in[(size_t)(by + r) * C + bx + tx]);
  __syncthreads();
#pragma unroll
  for (int r = ty; r < 32; r += 8)
    out[(size_t)(bx + r) * R + by + tx] = tile[tx][r];
}

// ---------------------------------------------------------------------------
// Legacy 128x128 gemm (proj GEMM: 512 blocks).
// ---------------------------------------------------------------------------
template <int CF32>
__global__ __launch_bounds__(256) void gemm_bt(
    const unsigned short* __restrict__ A,
    const unsigned short* __restrict__ Bt,
    void* __restrict__ Cv,
    int M, int N, int K, int ldc)
{
  __shared__ unsigned short As[2][128 * 32];
  __shared__ unsigned short Bs[2][128 * 32];
  const int tid  = threadIdx.x;
  const int lane = tid & 63;
  const int w    = tid >> 6;
  const int m0   = blockIdx.y * 128;
  const int n0   = blockIdx.x * 128;
  const int wm   = (w & 1) * 64;
  const int wn   = (w >> 1) * 64;

  const int srow = lane >> 2;
  const int scol = (lane & 3) * 8;
  const unsigned short* ga0 = A  + (size_t)(m0 + w * 16 + srow) * K + scol;
  const unsigned short* ga1 = ga0 + (size_t)64 * K;
  const unsigned short* gb0 = Bt + (size_t)(n0 + w * 16 + srow) * K + scol;
  const unsigned short* gb1 = gb0 + (size_t)64 * K;

  f32x4 acc[4][4];
#pragma unroll
  for (int i = 0; i < 4; i++)
#pragma unroll
    for (int j = 0; j < 4; j++) acc[i][j] = (f32x4){0.f, 0.f, 0.f, 0.f};

  const int frow = lane & 15;
  const int fcol = (lane >> 4) * 8;

  for (int kt = 0; kt < K; kt += 64) {
    __syncthreads();
    async16(ga0 + kt,      &As[0][w * 512]);
    async16(ga1 + kt,      &As[0][(4 + w) * 512]);
    async16(ga0 + kt + 32, &As[1][w * 512]);
    async16(ga1 + kt + 32, &As[1][(4 + w) * 512]);
    async16(gb0 + kt,      &Bs[0][w * 512]);
    async16(gb1 + kt,      &Bs[0][(4 + w) * 512]);
    async16(gb0 + kt + 32, &Bs[1][w * 512]);
    async16(gb1 + kt + 32, &Bs[1][(4 + w) * 512]);
    __syncthreads();

#pragma unroll
    for (int h = 0; h < 2; h++) {
      bf16x8 af[4], bfr[4];
#pragma unroll
      for (int i = 0; i < 4; i++)
        af[i] = *(const bf16x8*)&As[h][(wm + i * 16 + frow) * 32 + fcol];
#pragma unroll
      for (int i = 0; i < 4; i++)
        bfr[i] = *(const bf16x8*)&Bs[h][(wn + i * 16 + frow) * 32 + fcol];
#pragma unroll
      for (int mi = 0; mi < 4; mi++)
#pragma unroll
        for (int ni = 0; ni < 4; ni++)
          acc[mi][ni] = __builtin_amdgcn_mfma_f32_16x16x32_bf16(
              af[mi], bfr[ni], acc[mi][ni], 0, 0, 0);
    }
  }

  const int crow0 = m0 + wm + (lane >> 4) * 4;
  const int ccol0 = n0 + wn + (lane & 15);
  if (CF32) {
    float* Cf = (float*)Cv;
#pragma unroll
    for (int mi = 0; mi < 4; mi++)
#pragma unroll
      for (int i = 0; i < 4; i++) {
        const int row = crow0 + mi * 16 + i;
#pragma unroll
        for (int ni = 0; ni < 4; ni++)
          Cf[(size_t)row * ldc + ccol0 + ni * 16] = acc[mi][ni][i];
      }
  } else {
    unsigned short* Cb = (unsigned short*)Cv;
#pragma unroll
    for (int mi = 0; mi < 4; mi++)
#pragma unroll
      for (int i = 0; i < 4; i++) {
        const int row = crow0 + mi * 16 + i;
#pragma unroll
        for (int ni = 0; ni < 4; ni++)
          Cb[(size_t)row * ldc + ccol0 + ni * 16] = f2bf(acc[mi][ni][i]);
      }
  }
}

// ---------------------------------------------------------------------------
// 256x256 BK=64 phase-pipelined GEMM, v4.
// Round-4 change: __launch_bounds__(512, 1). Round 3's (512,2) promised
// 2 blocks/CU -> 128-VGPR cap; the pipeline's ~240-VGPR live set spilled
// (WRITE_SIZE 49->198 MB = scratch). LDS=128KiB already forces 1 block/CU,
// so min-waves=2 bought nothing. Schedule identical to r3:
//   G0 = a03+b01 (12, issued prev P3); G1 = b23 (4, @P0); G2 = a47 (8, @P1).
//   P0 a03xb01 | P1 a03xb23 | P2 a47xb01 | P3 a47xb23 (counted lgkmcnt,
//   spread prefetch, vmcnt(8) once per K-tile).
// ---------------------------------------------------------------------------
__device__ __forceinline__ void stage8(
    const unsigned short* gA, const unsigned short* gB,
    unsigned short* asb, unsigned short* bsb, int K, int kt, int lw)
{
#pragma unroll
  for (int j = 0; j < 4; j++)
    async16(gA + (size_t)j * 64 * K + (size_t)kt * 64, asb + j * 4096 + lw);
#pragma unroll
  for (int j = 0; j < 4; j++)
    async16(gB + (size_t)j * 64 * K + (size_t)kt * 64, bsb + j * 4096 + lw);
}

__global__ __launch_bounds__(512, 1) void gemm256(
    const unsigned short* __restrict__ A,
    const unsigned short* __restrict__ Bt,
    unsigned short* __restrict__ C,
    int K, int ldc, int ntiles, int nwg)
{
  __shared__ unsigned short As[2][256 * 64];
  __shared__ unsigned short Bs[2][256 * 64];

  // XCD-aware bijective swizzle (nwg % 8 == 0 by construction)
  int wg = blockIdx.x;
  wg = (wg & 7) * (nwg >> 3) + (wg >> 3);
  const int m0 = (wg / ntiles) * 256;
  const int n0 = (wg % ntiles) * 256;

  const int tid  = threadIdx.x;
  const int lane = tid & 63;
  const int w    = tid >> 6;
  const int wr   = w & 1;   // 2 M-groups
  const int wc   = w >> 1;  // 4 N-groups

  // staging map: thread t -> row t>>3, 16B-slot (t ^ (t>>3)) & 7
  const int srow  = tid >> 3;
  const int sslot = (tid ^ srow) & 7;
  const unsigned short* gA = A  + (size_t)(m0 + srow) * K + sslot * 8;
  const unsigned short* gB = Bt + (size_t)(n0 + srow) * K + sslot * 8;
  const int lw = w * 512;  // wave's 1 KiB slice within an 8 KiB chunk

  f32x4 acc[8][4];
#pragma unroll
  for (int i = 0; i < 8; i++)
#pragma unroll
    for (int j = 0; j < 4; j++) acc[i][j] = (f32x4){0.f, 0.f, 0.f, 0.f};

  const int frow = lane & 15;
  const int fq16 = (lane >> 4) * 16;         // byte offset of 16B k-slot
  const int axr  = (frow & 7) << 4;          // XOR key
  const int arow = (wr * 128 + frow) * 128;  // byte base, mi=0 kh=0
  const int brow = (wc * 64 + frow) * 128;

#define RDA(buf, mi, kh) \
  (*(const bf16x8*)((const char*)&As[buf][0] + ((arow + (mi) * 2048 + (kh) * 64 + fq16) ^ axr)))
#define RDB(buf, ni, kh) \
  (*(const bf16x8*)((const char*)&Bs[buf][0] + ((brow + (ni) * 2048 + (kh) * 64 + fq16) ^ axr)))
#define STG_A(c, kt2) async16(gA + (size_t)(c) * 64 * K + (size_t)(kt2) * 64, &As[p][(c) * 4096 + lw])
#define STG_B(c, kt2) async16(gB + (size_t)(c) * 64 * K + (size_t)(kt2) * 64, &Bs[p][(c) * 4096 + lw])

  stage8(gA, gB, &As[0][0], &Bs[0][0], K, 0, lw);
  stage8(gA, gB, &As[1][0], &Bs[1][0], K, 1, lw);
  asm volatile("s_waitcnt vmcnt(8)" ::: "memory");
  __builtin_amdgcn_s_barrier();
  FENCE;

  const int NT = K >> 6;
  bf16x8 a0[4][2], a4[4][2], b0[2][2], b2[2][2];

  // prologue G0 (buf 0): a03 + b01
#pragma unroll
  for (int mi = 0; mi < 4; mi++) { a0[mi][0] = RDA(0, mi, 0); a0[mi][1] = RDA(0, mi, 1); }
#pragma unroll
  for (int ni = 0; ni < 2; ni++) { b0[ni][0] = RDB(0, ni, 0); b0[ni][1] = RDB(0, ni, 1); }

  for (int kt = 0; kt < NT; ++kt) {
    const int p = kt & 1;

    // ---- P0: issue G1 (b23); lgkm(4) [G0 done]; MFMA a03 x b01
#pragma unroll
    for (int ni = 0; ni < 2; ni++) { b2[ni][0] = RDB(p, ni + 2, 0); b2[ni][1] = RDB(p, ni + 2, 1); }
    asm volatile("s_waitcnt lgkmcnt(4)" ::: "memory");
    __builtin_amdgcn_sched_barrier(0);
    __builtin_amdgcn_s_setprio(1);
#pragma unroll
    for (int mi = 0; mi < 4; mi++)
#pragma unroll
      for (int ni = 0; ni < 2; ni++)
#pragma unroll
        for (int kh = 0; kh < 2; kh++)
          acc[mi][ni] = __builtin_amdgcn_mfma_f32_16x16x32_bf16(
              a0[mi][kh], b0[ni][kh], acc[mi][ni], 0, 0, 0);
    __builtin_amdgcn_s_setprio(0);
    __builtin_amdgcn_s_barrier();   // B0
    FENCE;

    // ---- P1: stage A0,A2@kt+2; issue G2 (a47); lgkm(8) [G1 done]; MFMA a03 x b23
    if (kt + 2 < NT) { STG_A(0, kt + 2); STG_A(2, kt + 2); }
#pragma unroll
    for (int mi = 0; mi < 4; mi++) { a4[mi][0] = RDA(p, mi + 4, 0); a4[mi][1] = RDA(p, mi + 4, 1); }
    asm volatile("s_waitcnt lgkmcnt(8)" ::: "memory");
    __builtin_amdgcn_sched_barrier(0);
    __builtin_amdgcn_s_setprio(1);
#pragma unroll
    for (int mi = 0; mi < 4; mi++)
#pragma unroll
      for (int ni = 0; ni < 2; ni++)
#pragma unroll
        for (int kh = 0; kh < 2; kh++)
          acc[mi][ni + 2] = __builtin_amdgcn_mfma_f32_16x16x32_bf16(
              a0[mi][kh], b2[ni][kh], acc[mi][ni + 2], 0, 0, 0);
    __builtin_amdgcn_s_setprio(0);
    __builtin_amdgcn_s_barrier();   // B1
    FENCE;

    // ---- P2: stage B0,B1@kt+2; lgkm(0) [G2 done]; MFMA a47 x b01
    if (kt + 2 < NT) { STG_B(0, kt + 2); STG_B(1, kt + 2); }
    asm volatile("s_waitcnt lgkmcnt(0)" ::: "memory");
    __builtin_amdgcn_sched_barrier(0);
    __builtin_amdgcn_s_setprio(1);
#pragma unroll
    for (int mi = 0; mi < 4; mi++)
#pragma unroll
      for (int ni = 0; ni < 2; ni++)
#pragma unroll
        for (int kh = 0; kh < 2; kh++)
          acc[mi + 4][ni] = __builtin_amdgcn_mfma_f32_16x16x32_bf16(
              a4[mi][kh], b0[ni][kh], acc[mi + 4][ni], 0, 0, 0);
    __builtin_amdgcn_s_setprio(0);
    __builtin_amdgcn_s_barrier();   // B2
    FENCE;

    // ---- P3: stage B2,B3,A1,A3@kt+2; vmcnt(8); B3; issue G0' (next buf);
    //          MFMA a47 x b23 overlaps G0' drain.
    if (kt + 2 < NT) {
      STG_B(2, kt + 2); STG_B(3, kt + 2); STG_A(1, kt + 2); STG_A(3, kt + 2);
      asm volatile("s_waitcnt vmcnt(8)" ::: "memory");   // kt+1 landed; kt+2 in flight
    } else {
      asm volatile("s_waitcnt vmcnt(0)" ::: "memory");   // epilogue drain
    }
    __builtin_amdgcn_s_barrier();   // B3
    FENCE;
    if (kt + 1 < NT) {
      const int pn = p ^ 1;
#pragma unroll
      for (int mi = 0; mi < 4; mi++) { a0[mi][0] = RDA(pn, mi, 0); a0[mi][1] = RDA(pn, mi, 1); }
#pragma unroll
      for (int ni = 0; ni < 2; ni++) { b0[ni][0] = RDB(pn, ni, 0); b0[ni][1] = RDB(pn, ni, 1); }
    }
    __builtin_amdgcn_sched_barrier(0);
    __builtin_amdgcn_s_setprio(1);
#pragma unroll
    for (int mi = 0; mi < 4; mi++)
#pragma unroll
      for (int ni = 0; ni < 2; ni++)
#pragma unroll
        for (int kh = 0; kh < 2; kh++)
          acc[mi + 4][ni + 2] = __builtin_amdgcn_mfma_f32_16x16x32_bf16(
              a4[mi][kh], b2[ni][kh], acc[mi + 4][ni + 2], 0, 0, 0);
    __builtin_amdgcn_s_setprio(0);
  }
#undef RDA
#undef RDB
#undef STG_A
#undef STG_B

  // C/D layout (m89-verified): col = lane&15, row = (lane>>4)*4 + reg
  const int crow0 = m0 + wr * 128 + (lane >> 4) * 4;
  const int ccol0 = n0 + wc * 64 + frow;
#pragma unroll
  for (int mi = 0; mi < 8; mi++)
#pragma unroll
    for (int i = 0; i < 4; i++) {
      const size_t row = (size_t)(crow0 + mi * 16 + i);
#pragma unroll
      for (int ni = 0; ni < 4; ni++)
        C[row * ldc + ccol0 + ni * 16] = f2bf(acc[mi][ni][i]);
    }
}

// ---------------------------------------------------------------------------
// RoPE in-place on qkv cols [0,4096); 1/sqrt(128) folded into q half.
// ---------------------------------------------------------------------------
__global__ __launch_bounds__(256) void rope_qk(unsigned short* __restrict__ qkv)
{
  const int p   = blockIdx.x * 256 + threadIdx.x;
  const int row = p >> 11;
  const int col = (p & 2047) * 2;
  const int t   = row & (TSEQ - 1);
  const int hd  = col & 127;
  const float theta = exp2f((float)hd * -0.1038102531f);
  const float ang   = (float)t * theta;
  float s, c;
  sincosf(ang, &s, &c);
  const float sc = (col < 2048) ? 0.08838834764831845f : 1.0f;
  uint32_t* ptr = (uint32_t*)(qkv + (size_t)row * 6144 + col);
  const uint32_t u = *ptr;
  const float x0 = bf2f((unsigned short)(u & 0xffffu));
  const float x1 = bf2f((unsigned short)(u >> 16));
  const float o0 = (x0 * c - x1 * s) * sc;
  const float o1 = (x1 * c + x0 * s) * sc;
  *ptr = (uint32_t)f2bf(o0) | ((uint32_t)f2bf(o1) << 16);
}

// ---------------------------------------------------------------------------
// Repack V: qkv cols [4096,6144) -> Vtg[b][h][d=128][t=2048]
// ---------------------------------------------------------------------------
__global__ __launch_bounds__(256) void repack_v(
    const unsigned short* __restrict__ qkv, unsigned short* __restrict__ Vtg)
{
  __shared__ unsigned short tile[32][33];
  const int tt = blockIdx.x * 32;
  const int dd = blockIdx.y * 32;
  const int bh = blockIdx.z;
  const int b  = bh >> 4, h = bh & 15;
  const int tx = threadIdx.x & 31;
  const int ty = threadIdx.x >> 5;
#pragma unroll
  for (int r = ty; r < 32; r += 8)
    tile[r][tx] = qkv[(size_t)(b * TSEQ + tt + r) * 6144 + 4096 + h * 128 + dd + tx];
  __syncthreads();
#pragma unroll
  for (int r = ty; r < 32; r += 8)
    Vtg[(size_t)bh * 262144 + (size_t)(dd + r) * TSEQ + tt + tx] = tile[tx][r];
}

// ---------------------------------------------------------------------------
// Flash attention. block = (b,h,128 q-rows), 4 waves x 32 q-rows, K-chunk 64.
// ---------------------------------------------------------------------------
__global__ __launch_bounds__(256) void attn(
    const unsigned short* __restrict__ qkv,  // (4096,6144) rope'd, q pre-scaled
    const unsigned short* __restrict__ Vtg,  // (32,128,2048)
    unsigned short* __restrict__ y)          // (4096,2048)
{
  __shared__ unsigned short Ks[64 * 136];
  __shared__ unsigned short Vs[144 * 72];
  __shared__ unsigned short Ps[4][32 * 72];

  const int tid  = threadIdx.x;
  const int lane = tid & 63;
  const int w    = tid >> 6;
  const int q0   = blockIdx.x * 128;
  const int h    = blockIdx.y;
  const int b    = blockIdx.z;
  const int bh   = b * 16 + h;
  const int quad = lane >> 4;
  const int l15  = lane & 15;
  const int kq   = quad * 8;

  for (int idx = tid; idx < 16 * 72; idx += 256)
    Vs[128 * 72 + idx] = (idx < 72) ? (unsigned short)0x3F80 : (unsigned short)0;

  bf16x8 qa[2][4];
#pragma unroll
  for (int mt = 0; mt < 2; mt++) {
    const unsigned short* gQ =
        qkv + (size_t)(b * TSEQ + q0 + w * 32 + mt * 16 + l15) * 6144 + h * 128 + kq;
#pragma unroll
    for (int dc = 0; dc < 4; dc++) qa[mt][dc] = *(const bf16x8*)(gQ + dc * 32);
  }

  f32x4 ot[2][9];
#pragma unroll
  for (int mt = 0; mt < 2; mt++)
#pragma unroll
    for (int nt = 0; nt < 9; nt++) ot[mt][nt] = (f32x4){0.f, 0.f, 0.f, 0.f};

  const int krow = tid >> 2;
  const int kd   = (tid & 3) * 32;
  const unsigned short* gK = qkv + (size_t)(b * TSEQ) * 6144 + 2048 + h * 128 + kd;
  const int vd = tid >> 1;
  const int vc = (tid & 1) * 32;
  const unsigned short* gVt = Vtg + (size_t)bh * 262144 + (size_t)vd * TSEQ + vc;

  for (int kb = 0; kb < TSEQ; kb += 64) {
    __syncthreads();
    {
      const unsigned short* pk = gK + (size_t)(kb + krow) * 6144;
#pragma unroll
      for (int j = 0; j < 4; j++)
        *(us8*)&Ks[krow * 136 + kd + j * 8] = *(const us8*)(pk + j * 8);
      const unsigned short* pv = gVt + kb;
#pragma unroll
      for (int j = 0; j < 4; j++)
        *(us8*)&Vs[vd * 72 + vc + j * 8] = *(const us8*)(pv + j * 8);
    }
    __syncthreads();

    f32x4 s[2][4];
#pragma unroll
    for (int mt = 0; mt < 2; mt++)
#pragma unroll
      for (int ct = 0; ct < 4; ct++) s[mt][ct] = (f32x4){0.f, 0.f, 0.f, 0.f};
#pragma unroll
    for (int dc = 0; dc < 4; dc++) {
#pragma unroll
      for (int ct = 0; ct < 4; ct++) {
        bf16x8 kf = *(const bf16x8*)&Ks[(ct * 16 + l15) * 136 + dc * 32 + kq];
        s[0][ct] = __builtin_amdgcn_mfma_f32_16x16x32_bf16(qa[0][dc], kf, s[0][ct], 0, 0, 0);
        s[1][ct] = __builtin_amdgcn_mfma_f32_16x16x32_bf16(qa[1][dc], kf, s[1][ct], 0, 0, 0);
      }
    }

    unsigned short* pw = &Ps[w][0];
#pragma unroll
    for (int mt = 0; mt < 2; mt++)
#pragma unroll
      for (int ct = 0; ct < 4; ct++)
#pragma unroll
        for (int i = 0; i < 4; i++)
          pw[(mt * 16 + quad * 4 + i) * 72 + ct * 16 + l15] =
              f2bf_trunc(__expf(fminf(s[mt][ct][i], 30.f)));

    __asm__ volatile("s_waitcnt lgkmcnt(0)" ::: "memory");

#pragma unroll
    for (int kc = 0; kc < 2; kc++) {
      bf16x8 pa0 = *(const bf16x8*)&pw[(l15) * 72 + kc * 32 + kq];
      bf16x8 pa1 = *(const bf16x8*)&pw[(16 + l15) * 72 + kc * 32 + kq];
#pragma unroll
      for (int nt = 0; nt < 9; nt++) {
        bf16x8 vb = *(const bf16x8*)&Vs[(nt * 16 + l15) * 72 + kc * 32 + kq];
        ot[0][nt] = __builtin_amdgcn_mfma_f32_16x16x32_bf16(pa0, vb, ot[0][nt], 0, 0, 0);
        ot[1][nt] = __builtin_amdgcn_mfma_f32_16x16x32_bf16(pa1, vb, ot[1][nt], 0, 0, 0);
      }
    }
  }

#pragma unroll
  for (int mt = 0; mt < 2; mt++) {
    unsigned short* gy =
        y + (size_t)(b * TSEQ + q0 + w * 32 + mt * 16 + quad * 4) * 2048 + h * 128 + l15;
#pragma unroll
    for (int i = 0; i < 4; i++) {
      const float inv = 1.0f / __shfl(ot[mt][8][i], lane & 48);
#pragma unroll
      for (int nt = 0; nt < 8; nt++)
        gy[(size_t)i * 2048 + nt * 16] = f2bf(ot[mt][nt][i] * inv);
    }
  }
}

// ---------------------------------------------------------------------------
extern "C" void kernel_launch(void* const* d_in, const int* in_sizes, int n_in,
                              void* d_out, int out_size, void* d_ws, size_t ws_size,
                              hipStream_t stream)
{
  const float* x      = (const float*)d_in[0];
  const float* w_attn = (const float*)d_in[1];
  const float* w_proj = (const float*)d_in[2];

  if (ws_size < 67108864u) return;

  char* ws = (char*)d_ws;
  unsigned short* qkv = (unsigned short*)(ws);              // 48 MiB
  unsigned short* xb  = (unsigned short*)(ws + 50331648);   // 16 MiB (then y)
  unsigned short* y   = xb;
  unsigned short* wT2 = (unsigned short*)(ws);              // 8 MiB, after attn
  unsigned short* wTa = (unsigned short*)d_out;             // 24 MiB scratch
  unsigned short* Vtg = (unsigned short*)d_out;             // 16 MiB scratch

  transpose_w<<<dim3(192, 64), 256, 0, stream>>>(w_attn, wTa, 2048, 6144);
  cvt_x<<<dim3(2048), 256, 0, stream>>>(x, xb);
  // QKV: M=4096 N=6144 K=2048, 16 x 24 = 384 tiles of 256^2
  gemm256<<<dim3(384), 512, 0, stream>>>(xb, wTa, qkv, 2048, 6144, 24, 384);
  rope_qk<<<dim3(32768), 256, 0, stream>>>(qkv);
  repack_v<<<dim3(64, 4, 32), 256, 0, stream>>>(qkv, Vtg);
  attn<<<dim3(16, 16, 2), 256, 0, stream>>>(qkv, Vtg, y);
  transpose_w<<<dim3(64, 64), 256, 0, stream>>>(w_proj, wT2, 2048, 2048);
  gemm_bt<1><<<dim3(16, 32), 256, 0, stream>>>(y, wT2, d_out, 4096, 2048, 2048, 2048);
}

// Round 5
// 435.960 us; speedup vs baseline: 1.3971x; 1.3906x over previous
//
#include <hip/hip_runtime.h>
#include <cstdint>
#include <cstddef>

typedef __attribute__((ext_vector_type(8))) short bf16x8;
typedef __attribute__((ext_vector_type(8))) unsigned short us8;
typedef __attribute__((ext_vector_type(4))) float f32x4;

#define TSEQ 2048

__device__ __forceinline__ unsigned short f2bf(float f) {
  union { float f; uint32_t u; } v; v.f = f;
  uint32_t u = v.u;
  uint32_t r = (u + 0x7FFFu + ((u >> 16) & 1u)) >> 16;
  return (unsigned short)r;
}
__device__ __forceinline__ unsigned short f2bf_trunc(float f) {
  union { float f; uint32_t u; } v; v.f = f;
  return (unsigned short)(v.u >> 16);
}
__device__ __forceinline__ float bf2f(unsigned short h) {
  union { uint32_t u; float f; } v; v.u = ((uint32_t)h) << 16;
  return v.f;
}

__device__ __forceinline__ void async16(const void* g, void* l) {
  __builtin_amdgcn_global_load_lds(
      (const __attribute__((address_space(1))) unsigned int*)g,
      (__attribute__((address_space(3))) unsigned int*)l,
      16, 0, 0);
}

#define FENCE asm volatile("" ::: "memory")

// ---------------------------------------------------------------------------
// x (fp32) -> xb (bf16), 16 elems/thread
// ---------------------------------------------------------------------------
__global__ __launch_bounds__(256) void cvt_x(
    const float* __restrict__ in, unsigned short* __restrict__ out)
{
  const size_t i = ((size_t)blockIdx.x * 256 + threadIdx.x) * 16;
  f32x4 a0 = *(const f32x4*)(in + i);
  f32x4 a1 = *(const f32x4*)(in + i + 4);
  f32x4 a2 = *(const f32x4*)(in + i + 8);
  f32x4 a3 = *(const f32x4*)(in + i + 12);
  us8 lo, hi;
#pragma unroll
  for (int j = 0; j < 4; j++) {
    lo[j] = f2bf(a0[j]); lo[j + 4] = f2bf(a1[j]);
    hi[j] = f2bf(a2[j]); hi[j + 4] = f2bf(a3[j]);
  }
  *(us8*)(out + i) = lo;
  *(us8*)(out + i + 8) = hi;
}

// ---------------------------------------------------------------------------
// out(C x R bf16) = transpose of in(R x C fp32)
// ---------------------------------------------------------------------------
__global__ __launch_bounds__(256) void transpose_w(
    const float* __restrict__ in, unsigned short* __restrict__ out,
    int R, int C)
{
  __shared__ unsigned short tile[32][33];
  const int bx = blockIdx.x * 32;
  const int by = blockIdx.y * 32;
  const int tx = threadIdx.x & 31;
  const int ty = threadIdx.x >> 5;
#pragma unroll
  for (int r = ty; r < 32; r += 8)
    tile[r][tx] = f2bf(in[(size_t)(by + r) * C + bx + tx]);
  __syncthreads();
#pragma unroll
  for (int r = ty; r < 32; r += 8)
    out[(size_t)(bx + r) * R + by + tx] = tile[tx][r];
}

// ---------------------------------------------------------------------------
// Legacy 128x128 gemm (proj GEMM: 512 blocks).
// ---------------------------------------------------------------------------
template <int CF32>
__global__ __launch_bounds__(256) void gemm_bt(
    const unsigned short* __restrict__ A,
    const unsigned short* __restrict__ Bt,
    void* __restrict__ Cv,
    int M, int N, int K, int ldc)
{
  __shared__ unsigned short As[2][128 * 32];
  __shared__ unsigned short Bs[2][128 * 32];
  const int tid  = threadIdx.x;
  const int lane = tid & 63;
  const int w    = tid >> 6;
  const int m0   = blockIdx.y * 128;
  const int n0   = blockIdx.x * 128;
  const int wm   = (w & 1) * 64;
  const int wn   = (w >> 1) * 64;

  const int srow = lane >> 2;
  const int scol = (lane & 3) * 8;
  const unsigned short* ga0 = A  + (size_t)(m0 + w * 16 + srow) * K + scol;
  const unsigned short* ga1 = ga0 + (size_t)64 * K;
  const unsigned short* gb0 = Bt + (size_t)(n0 + w * 16 + srow) * K + scol;
  const unsigned short* gb1 = gb0 + (size_t)64 * K;

  f32x4 acc[4][4];
#pragma unroll
  for (int i = 0; i < 4; i++)
#pragma unroll
    for (int j = 0; j < 4; j++) acc[i][j] = (f32x4){0.f, 0.f, 0.f, 0.f};

  const int frow = lane & 15;
  const int fcol = (lane >> 4) * 8;

  for (int kt = 0; kt < K; kt += 64) {
    __syncthreads();
    async16(ga0 + kt,      &As[0][w * 512]);
    async16(ga1 + kt,      &As[0][(4 + w) * 512]);
    async16(ga0 + kt + 32, &As[1][w * 512]);
    async16(ga1 + kt + 32, &As[1][(4 + w) * 512]);
    async16(gb0 + kt,      &Bs[0][w * 512]);
    async16(gb1 + kt,      &Bs[0][(4 + w) * 512]);
    async16(gb0 + kt + 32, &Bs[1][w * 512]);
    async16(gb1 + kt + 32, &Bs[1][(4 + w) * 512]);
    __syncthreads();

#pragma unroll
    for (int h = 0; h < 2; h++) {
      bf16x8 af[4], bfr[4];
#pragma unroll
      for (int i = 0; i < 4; i++)
        af[i] = *(const bf16x8*)&As[h][(wm + i * 16 + frow) * 32 + fcol];
#pragma unroll
      for (int i = 0; i < 4; i++)
        bfr[i] = *(const bf16x8*)&Bs[h][(wn + i * 16 + frow) * 32 + fcol];
#pragma unroll
      for (int mi = 0; mi < 4; mi++)
#pragma unroll
        for (int ni = 0; ni < 4; ni++)
          acc[mi][ni] = __builtin_amdgcn_mfma_f32_16x16x32_bf16(
              af[mi], bfr[ni], acc[mi][ni], 0, 0, 0);
    }
  }

  const int crow0 = m0 + wm + (lane >> 4) * 4;
  const int ccol0 = n0 + wn + (lane & 15);
  if (CF32) {
    float* Cf = (float*)Cv;
#pragma unroll
    for (int mi = 0; mi < 4; mi++)
#pragma unroll
      for (int i = 0; i < 4; i++) {
        const int row = crow0 + mi * 16 + i;
#pragma unroll
        for (int ni = 0; ni < 4; ni++)
          Cf[(size_t)row * ldc + ccol0 + ni * 16] = acc[mi][ni][i];
      }
  } else {
    unsigned short* Cb = (unsigned short*)Cv;
#pragma unroll
    for (int mi = 0; mi < 4; mi++)
#pragma unroll
      for (int i = 0; i < 4; i++) {
        const int row = crow0 + mi * 16 + i;
#pragma unroll
        for (int ni = 0; ni < 4; ni++)
          Cb[(size_t)row * ldc + ccol0 + ni * 16] = f2bf(acc[mi][ni][i]);
      }
  }
}

// ---------------------------------------------------------------------------
// 256x128 BK=64 pipelined GEMM, v5.
// Round-5 root cause: with 8-wave blocks, residency = 2 waves/SIMD -> 256
// unified regs/wave. acc 128 AGPR (256^2 tile) forced arch-VGPR cap to 128;
// r3's pipeline live set (~150) structurally spilled (WRITE_SIZE 49->198MB).
// Fix: BN=128 -> per-wave 64x64, acc[4][4]=64 AGPR -> ~192 VGPRs free; the
// phase-ahead pipeline now fits. Also: grid 16x48=768 blocks = exactly 3
// full rounds (100% fill vs 75%). LDS 96KiB.
// Schedule per K-tile (2 phases, kt-unrolled x2 with named X/Y reg sets):
//   P0: issue b23 (4 ds); lgkm(4) [a,b01 done]; MFMA a x b01 (16);
//       lgkm(0); barrier B0   [all reads of buf p complete]
//   P1: stage kt+2 -> buf p (6 gload_lds); vmcnt(6) [kt+1 landed]; barrier B1;
//       issue a',b01' from buf p^1 (12 ds); MFMA a x b23 (16)  [overlap drain]
// vmcnt never 0 in steady state; 2 barriers/K-tile.
// ---------------------------------------------------------------------------
__global__ __launch_bounds__(512, 2) void gemm256(
    const unsigned short* __restrict__ A,
    const unsigned short* __restrict__ Bt,
    unsigned short* __restrict__ C,
    int K, int ldc, int ntiles, int nwg)
{
  __shared__ unsigned short As[2][256 * 64];   // 64 KiB
  __shared__ unsigned short Bs[2][128 * 64];   // 32 KiB

  // XCD-aware bijective swizzle (nwg % 8 == 0 by construction)
  int wg = blockIdx.x;
  wg = (wg & 7) * (nwg >> 3) + (wg >> 3);
  const int m0 = (wg / ntiles) * 256;
  const int n0 = (wg % ntiles) * 128;

  const int tid  = threadIdx.x;
  const int lane = tid & 63;
  const int w    = tid >> 6;
  const int wr   = w & 3;   // 4 M-groups (64 rows each)
  const int wc   = w >> 2;  // 2 N-groups (64 cols each)

  // staging map: thread t -> chunk-row t>>3, 16B-slot (t ^ (t>>3)) & 7
  // (inverse of the read-side XOR swizzle; rows unpermuted)
  const int srow  = tid >> 3;
  const int sslot = (tid ^ srow) & 7;
  const unsigned short* gA = A  + (size_t)(m0 + srow) * K + sslot * 8;
  const unsigned short* gB = Bt + (size_t)(n0 + srow) * K + sslot * 8;
  const int lw = w * 512;  // wave's 1 KiB slice within a 8 KiB (4096-elem) chunk

  f32x4 acc[4][4];
#pragma unroll
  for (int i = 0; i < 4; i++)
#pragma unroll
    for (int j = 0; j < 4; j++) acc[i][j] = (f32x4){0.f, 0.f, 0.f, 0.f};

  const int frow = lane & 15;
  const int fq16 = (lane >> 4) * 16;        // byte offset of 16B k-slot
  const int axr  = (frow & 7) << 4;         // XOR key
  const int arow = (wr * 64 + frow) * 128;  // byte base, mi=0 kh=0
  const int brow = (wc * 64 + frow) * 128;

#define RDA(buf, mi, kh) \
  (*(const bf16x8*)((const char*)&As[buf][0] + ((arow + (mi) * 2048 + (kh) * 64 + fq16) ^ axr)))
#define RDB(buf, ni, kh) \
  (*(const bf16x8*)((const char*)&Bs[buf][0] + ((brow + (ni) * 2048 + (kh) * 64 + fq16) ^ axr)))
#define STAGE6(buf, kt2)                                                          \
  do {                                                                            \
    async16(gA + (size_t)0 * 64 * K + (size_t)(kt2) * 64, &As[buf][0 * 4096 + lw]); \
    async16(gA + (size_t)1 * 64 * K + (size_t)(kt2) * 64, &As[buf][1 * 4096 + lw]); \
    async16(gA + (size_t)2 * 64 * K + (size_t)(kt2) * 64, &As[buf][2 * 4096 + lw]); \
    async16(gA + (size_t)3 * 64 * K + (size_t)(kt2) * 64, &As[buf][3 * 4096 + lw]); \
    async16(gB + (size_t)0 * 64 * K + (size_t)(kt2) * 64, &Bs[buf][0 * 4096 + lw]); \
    async16(gB + (size_t)1 * 64 * K + (size_t)(kt2) * 64, &Bs[buf][1 * 4096 + lw]); \
  } while (0)

  // ---- prologue: stage kt0 -> buf0, kt1 -> buf1; wait kt0; read G0(buf0)
  STAGE6(0, 0);
  STAGE6(1, 1);
  asm volatile("s_waitcnt vmcnt(6)" ::: "memory");
  __builtin_amdgcn_s_barrier();
  FENCE;

  bf16x8 aX[4][2], aY[4][2], b01X[2][2], b23X[2][2], b01Y[2][2], b23Y[2][2];
#pragma unroll
  for (int mi = 0; mi < 4; mi++) { aX[mi][0] = RDA(0, mi, 0); aX[mi][1] = RDA(0, mi, 1); }
#pragma unroll
  for (int ni = 0; ni < 2; ni++) { b01X[ni][0] = RDB(0, ni, 0); b01X[ni][1] = RDB(0, ni, 1); }

  const int NT = K >> 6;  // assumed even
  for (int kt = 0; kt < NT; kt += 2) {
    // ================= even tile kt: buf0, cur=X, next=Y =================
    // P0
#pragma unroll
    for (int ni = 0; ni < 2; ni++) { b23X[ni][0] = RDB(0, ni + 2, 0); b23X[ni][1] = RDB(0, ni + 2, 1); }
    asm volatile("s_waitcnt lgkmcnt(4)" ::: "memory");
    __builtin_amdgcn_sched_barrier(0);
    __builtin_amdgcn_s_setprio(1);
#pragma unroll
    for (int mi = 0; mi < 4; mi++)
#pragma unroll
      for (int ni = 0; ni < 2; ni++)
#pragma unroll
        for (int kh = 0; kh < 2; kh++)
          acc[mi][ni] = __builtin_amdgcn_mfma_f32_16x16x32_bf16(
              aX[mi][kh], b01X[ni][kh], acc[mi][ni], 0, 0, 0);
    __builtin_amdgcn_s_setprio(0);
    __builtin_amdgcn_sched_barrier(0);
    asm volatile("s_waitcnt lgkmcnt(0)" ::: "memory");
    __builtin_amdgcn_s_barrier();   // B0: all reads of buf0 complete
    FENCE;
    // P1
    if (kt + 2 < NT) {
      STAGE6(0, kt + 2);
      asm volatile("s_waitcnt vmcnt(6)" ::: "memory");   // kt+1 landed; kt+2 in flight
    } else {
      asm volatile("s_waitcnt vmcnt(0)" ::: "memory");
    }
    __builtin_amdgcn_s_barrier();   // B1: kt+1 (buf1) visible to all
    FENCE;
    {
#pragma unroll
      for (int mi = 0; mi < 4; mi++) { aY[mi][0] = RDA(1, mi, 0); aY[mi][1] = RDA(1, mi, 1); }
#pragma unroll
      for (int ni = 0; ni < 2; ni++) { b01Y[ni][0] = RDB(1, ni, 0); b01Y[ni][1] = RDB(1, ni, 1); }
    }
    __builtin_amdgcn_sched_barrier(0);
    __builtin_amdgcn_s_setprio(1);
#pragma unroll
    for (int mi = 0; mi < 4; mi++)
#pragma unroll
      for (int ni = 0; ni < 2; ni++)
#pragma unroll
        for (int kh = 0; kh < 2; kh++)
          acc[mi][ni + 2] = __builtin_amdgcn_mfma_f32_16x16x32_bf16(
              aX[mi][kh], b23X[ni][kh], acc[mi][ni + 2], 0, 0, 0);
    __builtin_amdgcn_s_setprio(0);

    // ================= odd tile kt+1: buf1, cur=Y, next=X =================
    // P0
#pragma unroll
    for (int ni = 0; ni < 2; ni++) { b23Y[ni][0] = RDB(1, ni + 2, 0); b23Y[ni][1] = RDB(1, ni + 2, 1); }
    asm volatile("s_waitcnt lgkmcnt(4)" ::: "memory");
    __builtin_amdgcn_sched_barrier(0);
    __builtin_amdgcn_s_setprio(1);
#pragma unroll
    for (int mi = 0; mi < 4; mi++)
#pragma unroll
      for (int ni = 0; ni < 2; ni++)
#pragma unroll
        for (int kh = 0; kh < 2; kh++)
          acc[mi][ni] = __builtin_amdgcn_mfma_f32_16x16x32_bf16(
              aY[mi][kh], b01Y[ni][kh], acc[mi][ni], 0, 0, 0);
    __builtin_amdgcn_s_setprio(0);
    __builtin_amdgcn_sched_barrier(0);
    asm volatile("s_waitcnt lgkmcnt(0)" ::: "memory");
    __builtin_amdgcn_s_barrier();   // B0': all reads of buf1 complete
    FENCE;
    // P1
    if (kt + 3 < NT) {
      STAGE6(1, kt + 3);
      asm volatile("s_waitcnt vmcnt(6)" ::: "memory");
    } else {
      asm volatile("s_waitcnt vmcnt(0)" ::: "memory");
    }
    __builtin_amdgcn_s_barrier();   // B1': kt+2 (buf0) visible to all
    FENCE;
    if (kt + 2 < NT) {
#pragma unroll
      for (int mi = 0; mi < 4; mi++) { aX[mi][0] = RDA(0, mi, 0); aX[mi][1] = RDA(0, mi, 1); }
#pragma unroll
      for (int ni = 0; ni < 2; ni++) { b01X[ni][0] = RDB(0, ni, 0); b01X[ni][1] = RDB(0, ni, 1); }
    }
    __builtin_amdgcn_sched_barrier(0);
    __builtin_amdgcn_s_setprio(1);
#pragma unroll
    for (int mi = 0; mi < 4; mi++)
#pragma unroll
      for (int ni = 0; ni < 2; ni++)
#pragma unroll
        for (int kh = 0; kh < 2; kh++)
          acc[mi][ni + 2] = __builtin_amdgcn_mfma_f32_16x16x32_bf16(
              aY[mi][kh], b23Y[ni][kh], acc[mi][ni + 2], 0, 0, 0);
    __builtin_amdgcn_s_setprio(0);
  }
#undef RDA
#undef RDB
#undef STAGE6

  // C/D layout (m89-verified): col = lane&15, row = (lane>>4)*4 + reg
  const int crow0 = m0 + wr * 64 + (lane >> 4) * 4;
  const int ccol0 = n0 + wc * 64 + frow;
#pragma unroll
  for (int mi = 0; mi < 4; mi++)
#pragma unroll
    for (int i = 0; i < 4; i++) {
      const size_t row = (size_t)(crow0 + mi * 16 + i);
#pragma unroll
      for (int ni = 0; ni < 4; ni++)
        C[row * ldc + ccol0 + ni * 16] = f2bf(acc[mi][ni][i]);
    }
}

// ---------------------------------------------------------------------------
// RoPE in-place on qkv cols [0,4096); 1/sqrt(128) folded into q half.
// ---------------------------------------------------------------------------
__global__ __launch_bounds__(256) void rope_qk(unsigned short* __restrict__ qkv)
{
  const int p   = blockIdx.x * 256 + threadIdx.x;
  const int row = p >> 11;
  const int col = (p & 2047) * 2;
  const int t   = row & (TSEQ - 1);
  const int hd  = col & 127;
  const float theta = exp2f((float)hd * -0.1038102531f);
  const float ang   = (float)t * theta;
  float s, c;
  sincosf(ang, &s, &c);
  const float sc = (col < 2048) ? 0.08838834764831845f : 1.0f;
  uint32_t* ptr = (uint32_t*)(qkv + (size_t)row * 6144 + col);
  const uint32_t u = *ptr;
  const float x0 = bf2f((unsigned short)(u & 0xffffu));
  const float x1 = bf2f((unsigned short)(u >> 16));
  const float o0 = (x0 * c - x1 * s) * sc;
  const float o1 = (x1 * c + x0 * s) * sc;
  *ptr = (uint32_t)f2bf(o0) | ((uint32_t)f2bf(o1) << 16);
}

// ---------------------------------------------------------------------------
// Repack V: qkv cols [4096,6144) -> Vtg[b][h][d=128][t=2048]
// ---------------------------------------------------------------------------
__global__ __launch_bounds__(256) void repack_v(
    const unsigned short* __restrict__ qkv, unsigned short* __restrict__ Vtg)
{
  __shared__ unsigned short tile[32][33];
  const int tt = blockIdx.x * 32;
  const int dd = blockIdx.y * 32;
  const int bh = blockIdx.z;
  const int b  = bh >> 4, h = bh & 15;
  const int tx = threadIdx.x & 31;
  const int ty = threadIdx.x >> 5;
#pragma unroll
  for (int r = ty; r < 32; r += 8)
    tile[r][tx] = qkv[(size_t)(b * TSEQ + tt + r) * 6144 + 4096 + h * 128 + dd + tx];
  __syncthreads();
#pragma unroll
  for (int r = ty; r < 32; r += 8)
    Vtg[(size_t)bh * 262144 + (size_t)(dd + r) * TSEQ + tt + tx] = tile[tx][r];
}

// ---------------------------------------------------------------------------
// Flash attention. block = (b,h,128 q-rows), 4 waves x 32 q-rows, K-chunk 64.
// ---------------------------------------------------------------------------
__global__ __launch_bounds__(256) void attn(
    const unsigned short* __restrict__ qkv,  // (4096,6144) rope'd, q pre-scaled
    const unsigned short* __restrict__ Vtg,  // (32,128,2048)
    unsigned short* __restrict__ y)          // (4096,2048)
{
  __shared__ unsigned short Ks[64 * 136];
  __shared__ unsigned short Vs[144 * 72];
  __shared__ unsigned short Ps[4][32 * 72];

  const int tid  = threadIdx.x;
  const int lane = tid & 63;
  const int w    = tid >> 6;
  const int q0   = blockIdx.x * 128;
  const int h    = blockIdx.y;
  const int b    = blockIdx.z;
  const int bh   = b * 16 + h;
  const int quad = lane >> 4;
  const int l15  = lane & 15;
  const int kq   = quad * 8;

  for (int idx = tid; idx < 16 * 72; idx += 256)
    Vs[128 * 72 + idx] = (idx < 72) ? (unsigned short)0x3F80 : (unsigned short)0;

  bf16x8 qa[2][4];
#pragma unroll
  for (int mt = 0; mt < 2; mt++) {
    const unsigned short* gQ =
        qkv + (size_t)(b * TSEQ + q0 + w * 32 + mt * 16 + l15) * 6144 + h * 128 + kq;
#pragma unroll
    for (int dc = 0; dc < 4; dc++) qa[mt][dc] = *(const bf16x8*)(gQ + dc * 32);
  }

  f32x4 ot[2][9];
#pragma unroll
  for (int mt = 0; mt < 2; mt++)
#pragma unroll
    for (int nt = 0; nt < 9; nt++) ot[mt][nt] = (f32x4){0.f, 0.f, 0.f, 0.f};

  const int krow = tid >> 2;
  const int kd   = (tid & 3) * 32;
  const unsigned short* gK = qkv + (size_t)(b * TSEQ) * 6144 + 2048 + h * 128 + kd;
  const int vd = tid >> 1;
  const int vc = (tid & 1) * 32;
  const unsigned short* gVt = Vtg + (size_t)bh * 262144 + (size_t)vd * TSEQ + vc;

  for (int kb = 0; kb < TSEQ; kb += 64) {
    __syncthreads();
    {
      const unsigned short* pk = gK + (size_t)(kb + krow) * 6144;
#pragma unroll
      for (int j = 0; j < 4; j++)
        *(us8*)&Ks[krow * 136 + kd + j * 8] = *(const us8*)(pk + j * 8);
      const unsigned short* pv = gVt + kb;
#pragma unroll
      for (int j = 0; j < 4; j++)
        *(us8*)&Vs[vd * 72 + vc + j * 8] = *(const us8*)(pv + j * 8);
    }
    __syncthreads();

    f32x4 s[2][4];
#pragma unroll
    for (int mt = 0; mt < 2; mt++)
#pragma unroll
      for (int ct = 0; ct < 4; ct++) s[mt][ct] = (f32x4){0.f, 0.f, 0.f, 0.f};
#pragma unroll
    for (int dc = 0; dc < 4; dc++) {
#pragma unroll
      for (int ct = 0; ct < 4; ct++) {
        bf16x8 kf = *(const bf16x8*)&Ks[(ct * 16 + l15) * 136 + dc * 32 + kq];
        s[0][ct] = __builtin_amdgcn_mfma_f32_16x16x32_bf16(qa[0][dc], kf, s[0][ct], 0, 0, 0);
        s[1][ct] = __builtin_amdgcn_mfma_f32_16x16x32_bf16(qa[1][dc], kf, s[1][ct], 0, 0, 0);
      }
    }

    unsigned short* pw = &Ps[w][0];
#pragma unroll
    for (int mt = 0; mt < 2; mt++)
#pragma unroll
      for (int ct = 0; ct < 4; ct++)
#pragma unroll
        for (int i = 0; i < 4; i++)
          pw[(mt * 16 + quad * 4 + i) * 72 + ct * 16 + l15] =
              f2bf_trunc(__expf(fminf(s[mt][ct][i], 30.f)));

    __asm__ volatile("s_waitcnt lgkmcnt(0)" ::: "memory");

#pragma unroll
    for (int kc = 0; kc < 2; kc++) {
      bf16x8 pa0 = *(const bf16x8*)&pw[(l15) * 72 + kc * 32 + kq];
      bf16x8 pa1 = *(const bf16x8*)&pw[(16 + l15) * 72 + kc * 32 + kq];
#pragma unroll
      for (int nt = 0; nt < 9; nt++) {
        bf16x8 vb = *(const bf16x8*)&Vs[(nt * 16 + l15) * 72 + kc * 32 + kq];
        ot[0][nt] = __builtin_amdgcn_mfma_f32_16x16x32_bf16(pa0, vb, ot[0][nt], 0, 0, 0);
        ot[1][nt] = __builtin_amdgcn_mfma_f32_16x16x32_bf16(pa1, vb, ot[1][nt], 0, 0, 0);
      }
    }
  }

#pragma unroll
  for (int mt = 0; mt < 2; mt++) {
    unsigned short* gy =
        y + (size_t)(b * TSEQ + q0 + w * 32 + mt * 16 + quad * 4) * 2048 + h * 128 + l15;
#pragma unroll
    for (int i = 0; i < 4; i++) {
      const float inv = 1.0f / __shfl(ot[mt][8][i], lane & 48);
#pragma unroll
      for (int nt = 0; nt < 8; nt++)
        gy[(size_t)i * 2048 + nt * 16] = f2bf(ot[mt][nt][i] * inv);
    }
  }
}

// ---------------------------------------------------------------------------
extern "C" void kernel_launch(void* const* d_in, const int* in_sizes, int n_in,
                              void* d_out, int out_size, void* d_ws, size_t ws_size,
                              hipStream_t stream)
{
  const float* x      = (const float*)d_in[0];
  const float* w_attn = (const float*)d_in[1];
  const float* w_proj = (const float*)d_in[2];

  if (ws_size < 67108864u) return;

  char* ws = (char*)d_ws;
  unsigned short* qkv = (unsigned short*)(ws);              // 48 MiB
  unsigned short* xb  = (unsigned short*)(ws + 50331648);   // 16 MiB (then y)
  unsigned short* y   = xb;
  unsigned short* wT2 = (unsigned short*)(ws);              // 8 MiB, after attn
  unsigned short* wTa = (unsigned short*)d_out;             // 24 MiB scratch
  unsigned short* Vtg = (unsigned short*)d_out;             // 16 MiB scratch

  transpose_w<<<dim3(192, 64), 256, 0, stream>>>(w_attn, wTa, 2048, 6144);
  cvt_x<<<dim3(2048), 256, 0, stream>>>(x, xb);
  // QKV: M=4096 N=6144 K=2048, 16 x 48 = 768 tiles of 256x128 (3 full rounds)
  gemm256<<<dim3(768), 512, 0, stream>>>(xb, wTa, qkv, 2048, 6144, 48, 768);
  rope_qk<<<dim3(32768), 256, 0, stream>>>(qkv);
  repack_v<<<dim3(64, 4, 32), 256, 0, stream>>>(qkv, Vtg);
  attn<<<dim3(16, 16, 2), 256, 0, stream>>>(qkv, Vtg, y);
  transpose_w<<<dim3(64, 64), 256, 0, stream>>>(w_proj, wT2, 2048, 2048);
  gemm_bt<1><<<dim3(16, 32), 256, 0, stream>>>(y, wT2, d_out, 4096, 2048, 2048, 2048);
}

// Round 6
// 427.958 us; speedup vs baseline: 1.4232x; 1.0187x over previous
//
#include <hip/hip_runtime.h>
#include <cstdint>
#include <cstddef>

typedef __attribute__((ext_vector_type(8))) short bf16x8;
typedef __attribute__((ext_vector_type(8))) unsigned short us8;
typedef __attribute__((ext_vector_type(4))) float f32x4;

#define TSEQ 2048

__device__ __forceinline__ unsigned short f2bf(float f) {
  union { float f; uint32_t u; } v; v.f = f;
  uint32_t u = v.u;
  uint32_t r = (u + 0x7FFFu + ((u >> 16) & 1u)) >> 16;
  return (unsigned short)r;
}
__device__ __forceinline__ unsigned short f2bf_trunc(float f) {
  union { float f; uint32_t u; } v; v.f = f;
  return (unsigned short)(v.u >> 16);
}
__device__ __forceinline__ float bf2f(unsigned short h) {
  union { uint32_t u; float f; } v; v.u = ((uint32_t)h) << 16;
  return v.f;
}

__device__ __forceinline__ void async16(const void* g, void* l) {
  __builtin_amdgcn_global_load_lds(
      (const __attribute__((address_space(1))) unsigned int*)g,
      (__attribute__((address_space(3))) unsigned int*)l,
      16, 0, 0);
}

// ---------------------------------------------------------------------------
// x (fp32) -> xb (bf16), 16 elems/thread
// ---------------------------------------------------------------------------
__global__ __launch_bounds__(256) void cvt_x(
    const float* __restrict__ in, unsigned short* __restrict__ out)
{
  const size_t i = ((size_t)blockIdx.x * 256 + threadIdx.x) * 16;
  f32x4 a0 = *(const f32x4*)(in + i);
  f32x4 a1 = *(const f32x4*)(in + i + 4);
  f32x4 a2 = *(const f32x4*)(in + i + 8);
  f32x4 a3 = *(const f32x4*)(in + i + 12);
  us8 lo, hi;
#pragma unroll
  for (int j = 0; j < 4; j++) {
    lo[j] = f2bf(a0[j]); lo[j + 4] = f2bf(a1[j]);
    hi[j] = f2bf(a2[j]); hi[j + 4] = f2bf(a3[j]);
  }
  *(us8*)(out + i) = lo;
  *(us8*)(out + i + 8) = hi;
}

// ---------------------------------------------------------------------------
// out(C x R bf16) = transpose of in(R x C fp32)
// ---------------------------------------------------------------------------
__global__ __launch_bounds__(256) void transpose_w(
    const float* __restrict__ in, unsigned short* __restrict__ out,
    int R, int C)
{
  __shared__ unsigned short tile[32][33];
  const int bx = blockIdx.x * 32;
  const int by = blockIdx.y * 32;
  const int tx = threadIdx.x & 31;
  const int ty = threadIdx.x >> 5;
#pragma unroll
  for (int r = ty; r < 32; r += 8)
    tile[r][tx] = f2bf(in[(size_t)(by + r) * C + bx + tx]);
  __syncthreads();
#pragma unroll
  for (int r = ty; r < 32; r += 8)
    out[(size_t)(bx + r) * R + by + tx] = tile[tx][r];
}

// ---------------------------------------------------------------------------
// 128x128 BK=64 gemm (m97-structure, 838 TF @ QKV shape — the known-good
// workhorse; 5 rounds of 256-tile pipelining never beat it from HIP source).
// ---------------------------------------------------------------------------
template <int CF32>
__global__ __launch_bounds__(256) void gemm_bt(
    const unsigned short* __restrict__ A,
    const unsigned short* __restrict__ Bt,
    void* __restrict__ Cv,
    int M, int N, int K, int ldc)
{
  __shared__ unsigned short As[2][128 * 32];
  __shared__ unsigned short Bs[2][128 * 32];
  const int tid  = threadIdx.x;
  const int lane = tid & 63;
  const int w    = tid >> 6;
  const int m0   = blockIdx.y * 128;
  const int n0   = blockIdx.x * 128;
  const int wm   = (w & 1) * 64;
  const int wn   = (w >> 1) * 64;

  const int srow = lane >> 2;
  const int scol = (lane & 3) * 8;
  const unsigned short* ga0 = A  + (size_t)(m0 + w * 16 + srow) * K + scol;
  const unsigned short* ga1 = ga0 + (size_t)64 * K;
  const unsigned short* gb0 = Bt + (size_t)(n0 + w * 16 + srow) * K + scol;
  const unsigned short* gb1 = gb0 + (size_t)64 * K;

  f32x4 acc[4][4];
#pragma unroll
  for (int i = 0; i < 4; i++)
#pragma unroll
    for (int j = 0; j < 4; j++) acc[i][j] = (f32x4){0.f, 0.f, 0.f, 0.f};

  const int frow = lane & 15;
  const int fcol = (lane >> 4) * 8;

  for (int kt = 0; kt < K; kt += 64) {
    __syncthreads();
    async16(ga0 + kt,      &As[0][w * 512]);
    async16(ga1 + kt,      &As[0][(4 + w) * 512]);
    async16(ga0 + kt + 32, &As[1][w * 512]);
    async16(ga1 + kt + 32, &As[1][(4 + w) * 512]);
    async16(gb0 + kt,      &Bs[0][w * 512]);
    async16(gb1 + kt,      &Bs[0][(4 + w) * 512]);
    async16(gb0 + kt + 32, &Bs[1][w * 512]);
    async16(gb1 + kt + 32, &Bs[1][(4 + w) * 512]);
    __syncthreads();

#pragma unroll
    for (int h = 0; h < 2; h++) {
      bf16x8 af[4], bfr[4];
#pragma unroll
      for (int i = 0; i < 4; i++)
        af[i] = *(const bf16x8*)&As[h][(wm + i * 16 + frow) * 32 + fcol];
#pragma unroll
      for (int i = 0; i < 4; i++)
        bfr[i] = *(const bf16x8*)&Bs[h][(wn + i * 16 + frow) * 32 + fcol];
#pragma unroll
      for (int mi = 0; mi < 4; mi++)
#pragma unroll
        for (int ni = 0; ni < 4; ni++)
          acc[mi][ni] = __builtin_amdgcn_mfma_f32_16x16x32_bf16(
              af[mi], bfr[ni], acc[mi][ni], 0, 0, 0);
    }
  }

  const int crow0 = m0 + wm + (lane >> 4) * 4;
  const int ccol0 = n0 + wn + (lane & 15);
  if (CF32) {
    float* Cf = (float*)Cv;
#pragma unroll
    for (int mi = 0; mi < 4; mi++)
#pragma unroll
      for (int i = 0; i < 4; i++) {
        const int row = crow0 + mi * 16 + i;
#pragma unroll
        for (int ni = 0; ni < 4; ni++)
          Cf[(size_t)row * ldc + ccol0 + ni * 16] = acc[mi][ni][i];
      }
  } else {
    unsigned short* Cb = (unsigned short*)Cv;
#pragma unroll
    for (int mi = 0; mi < 4; mi++)
#pragma unroll
      for (int i = 0; i < 4; i++) {
        const int row = crow0 + mi * 16 + i;
#pragma unroll
        for (int ni = 0; ni < 4; ni++)
          Cb[(size_t)row * ldc + ccol0 + ni * 16] = f2bf(acc[mi][ni][i]);
      }
  }
}

// ---------------------------------------------------------------------------
// RoPE in-place on qkv cols [0,4096); 1/sqrt(128) folded into q half.
// ---------------------------------------------------------------------------
__global__ __launch_bounds__(256) void rope_qk(unsigned short* __restrict__ qkv)
{
  const int p   = blockIdx.x * 256 + threadIdx.x;
  const int row = p >> 11;
  const int col = (p & 2047) * 2;
  const int t   = row & (TSEQ - 1);
  const int hd  = col & 127;
  const float theta = exp2f((float)hd * -0.1038102531f);
  const float ang   = (float)t * theta;
  float s, c;
  sincosf(ang, &s, &c);
  const float sc = (col < 2048) ? 0.08838834764831845f : 1.0f;
  uint32_t* ptr = (uint32_t*)(qkv + (size_t)row * 6144 + col);
  const uint32_t u = *ptr;
  const float x0 = bf2f((unsigned short)(u & 0xffffu));
  const float x1 = bf2f((unsigned short)(u >> 16));
  const float o0 = (x0 * c - x1 * s) * sc;
  const float o1 = (x1 * c + x0 * s) * sc;
  *ptr = (uint32_t)f2bf(o0) | ((uint32_t)f2bf(o1) << 16);
}

// ---------------------------------------------------------------------------
// Repack V: qkv cols [4096,6144) -> Vtg[b][h][d=128][t=2048]
// ---------------------------------------------------------------------------
__global__ __launch_bounds__(256) void repack_v(
    const unsigned short* __restrict__ qkv, unsigned short* __restrict__ Vtg)
{
  __shared__ unsigned short tile[32][33];
  const int tt = blockIdx.x * 32;
  const int dd = blockIdx.y * 32;
  const int bh = blockIdx.z;
  const int b  = bh >> 4, h = bh & 15;
  const int tx = threadIdx.x & 31;
  const int ty = threadIdx.x >> 5;
#pragma unroll
  for (int r = ty; r < 32; r += 8)
    tile[r][tx] = qkv[(size_t)(b * TSEQ + tt + r) * 6144 + 4096 + h * 128 + dd + tx];
  __syncthreads();
#pragma unroll
  for (int r = ty; r < 32; r += 8)
    Vtg[(size_t)bh * 262144 + (size_t)(dd + r) * TSEQ + tt + tx] = tile[tx][r];
}

// ---------------------------------------------------------------------------
// Flash attention. block = (b,h,128 q-rows), 4 waves x 32 q-rows, K-chunk 64.
// Round-6 changes (T14 + T5):
//  - async-STAGE split: K/V chunk kb+64 prefetched into 32 regs right after
//    the stage barrier; consumed (reg->LDS) at top of next iteration. The
//    ~200-900cy global latency hides under the 68-MFMA compute phase
//    (previously fully exposed between the two barriers every iteration).
//  - s_setprio(1) around the QK^T and PV MFMA clusters (waves here are
//    independent, the regime where setprio pays — m191).
// ---------------------------------------------------------------------------
__global__ __launch_bounds__(256) void attn(
    const unsigned short* __restrict__ qkv,  // (4096,6144) rope'd, q pre-scaled
    const unsigned short* __restrict__ Vtg,  // (32,128,2048)
    unsigned short* __restrict__ y)          // (4096,2048)
{
  __shared__ unsigned short Ks[64 * 136];
  __shared__ unsigned short Vs[144 * 72];
  __shared__ unsigned short Ps[4][32 * 72];

  const int tid  = threadIdx.x;
  const int lane = tid & 63;
  const int w    = tid >> 6;
  const int q0   = blockIdx.x * 128;
  const int h    = blockIdx.y;
  const int b    = blockIdx.z;
  const int bh   = b * 16 + h;
  const int quad = lane >> 4;
  const int l15  = lane & 15;
  const int kq   = quad * 8;

  for (int idx = tid; idx < 16 * 72; idx += 256)
    Vs[128 * 72 + idx] = (idx < 72) ? (unsigned short)0x3F80 : (unsigned short)0;

  bf16x8 qa[2][4];
#pragma unroll
  for (int mt = 0; mt < 2; mt++) {
    const unsigned short* gQ =
        qkv + (size_t)(b * TSEQ + q0 + w * 32 + mt * 16 + l15) * 6144 + h * 128 + kq;
#pragma unroll
    for (int dc = 0; dc < 4; dc++) qa[mt][dc] = *(const bf16x8*)(gQ + dc * 32);
  }

  f32x4 ot[2][9];
#pragma unroll
  for (int mt = 0; mt < 2; mt++)
#pragma unroll
    for (int nt = 0; nt < 9; nt++) ot[mt][nt] = (f32x4){0.f, 0.f, 0.f, 0.f};

  const int krow = tid >> 2;
  const int kd   = (tid & 3) * 32;
  const unsigned short* gK = qkv + (size_t)(b * TSEQ) * 6144 + 2048 + h * 128 + kd;
  const int vd = tid >> 1;
  const int vc = (tid & 1) * 32;
  const unsigned short* gVt = Vtg + (size_t)bh * 262144 + (size_t)vd * TSEQ + vc;

  // T14 prologue: chunk 0 -> regs
  us8 kreg[4], vreg[4];
  {
    const unsigned short* pk = gK + (size_t)krow * 6144;
#pragma unroll
    for (int j = 0; j < 4; j++) kreg[j] = *(const us8*)(pk + j * 8);
#pragma unroll
    for (int j = 0; j < 4; j++) vreg[j] = *(const us8*)(gVt + j * 8);
  }

  for (int kb = 0; kb < TSEQ; kb += 64) {
    __syncthreads();
    // write the prefetched chunk to LDS
#pragma unroll
    for (int j = 0; j < 4; j++)
      *(us8*)&Ks[krow * 136 + kd + j * 8] = kreg[j];
#pragma unroll
    for (int j = 0; j < 4; j++)
      *(us8*)&Vs[vd * 72 + vc + j * 8] = vreg[j];
    __syncthreads();

    // issue next chunk's global loads; they drain under the MFMA/exp phase
    if (kb + 64 < TSEQ) {
      const unsigned short* pk = gK + (size_t)(kb + 64 + krow) * 6144;
#pragma unroll
      for (int j = 0; j < 4; j++) kreg[j] = *(const us8*)(pk + j * 8);
      const unsigned short* pv = gVt + kb + 64;
#pragma unroll
      for (int j = 0; j < 4; j++) vreg[j] = *(const us8*)(pv + j * 8);
    }

    f32x4 s[2][4];
#pragma unroll
    for (int mt = 0; mt < 2; mt++)
#pragma unroll
      for (int ct = 0; ct < 4; ct++) s[mt][ct] = (f32x4){0.f, 0.f, 0.f, 0.f};
    __builtin_amdgcn_s_setprio(1);
#pragma unroll
    for (int dc = 0; dc < 4; dc++) {
#pragma unroll
      for (int ct = 0; ct < 4; ct++) {
        bf16x8 kf = *(const bf16x8*)&Ks[(ct * 16 + l15) * 136 + dc * 32 + kq];
        s[0][ct] = __builtin_amdgcn_mfma_f32_16x16x32_bf16(qa[0][dc], kf, s[0][ct], 0, 0, 0);
        s[1][ct] = __builtin_amdgcn_mfma_f32_16x16x32_bf16(qa[1][dc], kf, s[1][ct], 0, 0, 0);
      }
    }
    __builtin_amdgcn_s_setprio(0);

    unsigned short* pw = &Ps[w][0];
#pragma unroll
    for (int mt = 0; mt < 2; mt++)
#pragma unroll
      for (int ct = 0; ct < 4; ct++)
#pragma unroll
        for (int i = 0; i < 4; i++)
          pw[(mt * 16 + quad * 4 + i) * 72 + ct * 16 + l15] =
              f2bf_trunc(__expf(fminf(s[mt][ct][i], 30.f)));

    __asm__ volatile("s_waitcnt lgkmcnt(0)" ::: "memory");

    __builtin_amdgcn_s_setprio(1);
#pragma unroll
    for (int kc = 0; kc < 2; kc++) {
      bf16x8 pa0 = *(const bf16x8*)&pw[(l15) * 72 + kc * 32 + kq];
      bf16x8 pa1 = *(const bf16x8*)&pw[(16 + l15) * 72 + kc * 32 + kq];
#pragma unroll
      for (int nt = 0; nt < 9; nt++) {
        bf16x8 vb = *(const bf16x8*)&Vs[(nt * 16 + l15) * 72 + kc * 32 + kq];
        ot[0][nt] = __builtin_amdgcn_mfma_f32_16x16x32_bf16(pa0, vb, ot[0][nt], 0, 0, 0);
        ot[1][nt] = __builtin_amdgcn_mfma_f32_16x16x32_bf16(pa1, vb, ot[1][nt], 0, 0, 0);
      }
    }
    __builtin_amdgcn_s_setprio(0);
  }

#pragma unroll
  for (int mt = 0; mt < 2; mt++) {
    unsigned short* gy =
        y + (size_t)(b * TSEQ + q0 + w * 32 + mt * 16 + quad * 4) * 2048 + h * 128 + l15;
#pragma unroll
    for (int i = 0; i < 4; i++) {
      const float inv = 1.0f / __shfl(ot[mt][8][i], lane & 48);
#pragma unroll
      for (int nt = 0; nt < 8; nt++)
        gy[(size_t)i * 2048 + nt * 16] = f2bf(ot[mt][nt][i] * inv);
    }
  }
}

// ---------------------------------------------------------------------------
extern "C" void kernel_launch(void* const* d_in, const int* in_sizes, int n_in,
                              void* d_out, int out_size, void* d_ws, size_t ws_size,
                              hipStream_t stream)
{
  const float* x      = (const float*)d_in[0];
  const float* w_attn = (const float*)d_in[1];
  const float* w_proj = (const float*)d_in[2];

  if (ws_size < 67108864u) return;

  char* ws = (char*)d_ws;
  unsigned short* qkv = (unsigned short*)(ws);              // 48 MiB
  unsigned short* xb  = (unsigned short*)(ws + 50331648);   // 16 MiB (then y)
  unsigned short* y   = xb;
  unsigned short* wT2 = (unsigned short*)(ws);              // 8 MiB, after attn
  unsigned short* wTa = (unsigned short*)d_out;             // 24 MiB scratch
  unsigned short* Vtg = (unsigned short*)d_out;             // 16 MiB scratch

  transpose_w<<<dim3(192, 64), 256, 0, stream>>>(w_attn, wTa, 2048, 6144);
  cvt_x<<<dim3(2048), 256, 0, stream>>>(x, xb);
  gemm_bt<0><<<dim3(48, 32), 256, 0, stream>>>(xb, wTa, (void*)qkv, 4096, 6144, 2048, 6144);
  rope_qk<<<dim3(32768), 256, 0, stream>>>(qkv);
  repack_v<<<dim3(64, 4, 32), 256, 0, stream>>>(qkv, Vtg);
  attn<<<dim3(16, 16, 2), 256, 0, stream>>>(qkv, Vtg, y);
  transpose_w<<<dim3(64, 64), 256, 0, stream>>>(w_proj, wT2, 2048, 2048);
  gemm_bt<1><<<dim3(16, 32), 256, 0, stream>>>(y, wT2, d_out, 4096, 2048, 2048, 2048);
}